// Round 7
// baseline (460.484 us; speedup 1.0000x reference)
//
#include <hip/hip_runtime.h>
#include <hip/hip_bf16.h>

#define N_NODES 100000
#define N_EDGES 1600000
#define F_IN 165
#define KP0 192   // F_IN padded to multiple of 32
#define HID 128

#define NBKT 196   // ceil(N/512) coarse dst buckets (dst>>9)
#define EPB1 8192  // edges per block in coarse passes
#define NBLK1 196  // ceil(E/EPB1)
#define NSB 13     // src buckets (src>>13, 8192-node = 2MB stripes)

typedef __attribute__((ext_vector_type(8))) short bf16x8;
typedef __attribute__((ext_vector_type(4))) float f32x4;

__device__ __forceinline__ ushort f2bf(float f) {
    unsigned u = __float_as_uint(f);
    unsigned r = (u + 0x7fffu + ((u >> 16) & 1u)) >> 16;  // RNE
    return (ushort)r;
}
__device__ __forceinline__ float bflo(unsigned p) { return __uint_as_float(p << 16); }
__device__ __forceinline__ float bfhi(unsigned p) { return __uint_as_float(p & 0xffff0000u); }

// ---------------- src-bucket pre-sort (for gather L2 locality) ----------------

__global__ __launch_bounds__(256) void k_s1(const int* __restrict__ src, int* __restrict__ counts2, int E) {
    __shared__ int h[NSB];
    int t = threadIdx.x;
    if (t < NSB) h[t] = 0;
    __syncthreads();
    int base = blockIdx.x * EPB1;
    for (int i = 0; i < EPB1; i += 256) {
        int e = base + i + t;
        if (e < E) atomicAdd(&h[src[e] >> 13], 1);
    }
    __syncthreads();
    if (t < NSB) counts2[blockIdx.x * NSB + t] = h[t];
}

__global__ __launch_bounds__(64) void k_s2(const int* __restrict__ counts2, int* __restrict__ offs2) {
    __shared__ int tot[NSB], base[NSB];
    int t = threadIdx.x;
    if (t < NSB) {
        int s = 0;
        for (int b = 0; b < NBLK1; b++) s += counts2[b * NSB + t];
        tot[t] = s;
    }
    __syncthreads();
    if (t == 0) {
        int run = 0;
        for (int i = 0; i < NSB; i++) { base[i] = run; run += tot[i]; }
    }
    __syncthreads();
    if (t < NSB) {
        int run = base[t];
        for (int b = 0; b < NBLK1; b++) {
            offs2[b * NSB + t] = run;
            run += counts2[b * NSB + t];
        }
    }
}

__global__ __launch_bounds__(256) void k_s3(const int* __restrict__ src, const int* __restrict__ dst,
                                            const int* __restrict__ offs2, int2* __restrict__ ebuf2, int E) {
    __shared__ int cur[NSB];
    int t = threadIdx.x;
    if (t < NSB) cur[t] = offs2[blockIdx.x * NSB + t];
    __syncthreads();
    int base = blockIdx.x * EPB1;
    for (int i = 0; i < EPB1; i += 256) {
        int e = base + i + t;
        if (e < E) {
            int s = src[e], d = dst[e];
            int pos = atomicAdd(&cur[s >> 13], 1);
            ebuf2[pos] = make_int2(s, d);
        }
    }
}

// ---------------- CSR build via 2-level counting sort (stable over src order) ----------------

__global__ __launch_bounds__(256) void k_p1(const int2* __restrict__ ebuf2, int* __restrict__ counts, int E) {
    __shared__ int h[NBKT];
    int t = threadIdx.x;
    for (int i = t; i < NBKT; i += 256) h[i] = 0;
    __syncthreads();
    int base = blockIdx.x * EPB1;
    for (int i = 0; i < EPB1; i += 256) {
        int e = base + i + t;
        if (e < E) atomicAdd(&h[ebuf2[e].y >> 9], 1);
    }
    __syncthreads();
    for (int i = t; i < NBKT; i += 256) counts[blockIdx.x * NBKT + i] = h[i];
}

__global__ __launch_bounds__(256) void k_p2(const int* __restrict__ counts, int* __restrict__ offs,
                                            int* __restrict__ bbase, int* __restrict__ rowptr, int E) {
    __shared__ int s[256];
    int t = threadIdx.x;
    int tot = 0;
    if (t < NBKT) {
        for (int blk = 0; blk < NBLK1; blk++) tot += counts[blk * NBKT + t];
    }
    s[t] = (t < NBKT) ? tot : 0;
    __syncthreads();
    for (int off = 1; off < 256; off <<= 1) {
        int v = (t >= off) ? s[t - off] : 0;
        __syncthreads();
        s[t] += v;
        __syncthreads();
    }
    int base = s[t] - tot;  // exclusive
    if (t < NBKT) {
        bbase[t] = base;
        int run = base;
        for (int blk = 0; blk < NBLK1; blk++) {
            int c = counts[blk * NBKT + t];
            offs[blk * NBKT + t] = run;
            run += c;
        }
    }
    if (t == 0) rowptr[N_NODES] = E;
}

__global__ __launch_bounds__(256) void k_p3(const int2* __restrict__ ebuf2,
                                            const int* __restrict__ offs, int* __restrict__ ebuf, int E) {
    __shared__ int cur[NBKT];
    int t = threadIdx.x;
    for (int i = t; i < NBKT; i += 256) cur[i] = offs[blockIdx.x * NBKT + i];
    __syncthreads();
    int base = blockIdx.x * EPB1;
    for (int i = 0; i < EPB1; i += 256) {
        int e = base + i + t;
        if (e < E) {
            int2 ed = ebuf2[e];
            int b = ed.y >> 9;
            int pos = atomicAdd(&cur[b], 1);
            ebuf[pos] = ed.x | ((ed.y & 511) << 17);
        }
    }
}

__global__ __launch_bounds__(256) void k_p4(const int* __restrict__ ebuf, const int* __restrict__ bbase,
                                            int* __restrict__ rowptr, int* __restrict__ esrc, int E, int N) {
    __shared__ int fh[512], fex[512], fcur[512];
    __shared__ int sc[256];
    int t = threadIdx.x;
    int b = blockIdx.x;
    int base = bbase[b];
    int end = (b + 1 < NBKT) ? bbase[b + 1] : E;
    int cnt = end - base;
    fh[t] = 0; fh[t + 256] = 0; fcur[t] = 0; fcur[t + 256] = 0;
    __syncthreads();
    for (int i = t; i < cnt; i += 256) atomicAdd(&fh[(ebuf[base + i] >> 17) & 511], 1);
    __syncthreads();
    int a0 = fh[2 * t], a1 = fh[2 * t + 1];
    sc[t] = a0 + a1;
    __syncthreads();
    for (int off = 1; off < 256; off <<= 1) {
        int v = (t >= off) ? sc[t - off] : 0;
        __syncthreads();
        sc[t] += v;
        __syncthreads();
    }
    int ex = sc[t] - (a0 + a1);
    fex[2 * t] = ex;
    fex[2 * t + 1] = ex + a0;
    __syncthreads();
    int node0 = b << 9;
    for (int f = t; f < 512; f += 256) {
        int node = node0 + f;
        if (node < N) rowptr[node] = base + fex[f];
    }
    for (int i = t; i < cnt; i += 256) {
        int p = ebuf[base + i];
        int f = (p >> 17) & 511;
        int pos = base + fex[f] + atomicAdd(&fcur[f], 1);
        esrc[pos] = p & 0x1ffff;
    }
}

// ---------------- casts ----------------

__global__ __launch_bounds__(256) void k_cast_x(const float* __restrict__ x, ushort* __restrict__ xb, int NP) {
    int idx = blockIdx.x * 256 + threadIdx.x;
    if (idx >= NP * (KP0 / 8)) return;
    int row = idx / (KP0 / 8), j = idx % (KP0 / 8);
    int c0 = j * 8;
    ushort pk[8];
#pragma unroll
    for (int i = 0; i < 8; i++) {
        int c = c0 + i;
        float v = (row < N_NODES && c < F_IN) ? x[(size_t)row * F_IN + c] : 0.f;
        pk[i] = f2bf(v);
    }
    *(uint4*)(xb + (size_t)row * KP0 + c0) = *(uint4*)pk;
}

__global__ __launch_bounds__(256) void k_cast_w0(const float* __restrict__ Wl, const float* __restrict__ Wr,
                                                 short* __restrict__ Wb) {
    int idx = blockIdx.x * 256 + threadIdx.x;
    if (idx >= 256 * KP0) return;
    int row = idx / KP0, col = idx % KP0;
    const float* W = (row < 128) ? Wl : Wr;
    float v = (col < F_IN) ? W[(size_t)(row & 127) * F_IN + col] : 0.f;
    Wb[idx] = (short)f2bf(v);
}

__global__ __launch_bounds__(256) void k_cast_w12(const float* __restrict__ Wl, const float* __restrict__ Wr,
                                                  short* __restrict__ Wb) {
    int idx = blockIdx.x * 256 + threadIdx.x;
    if (idx >= 2 * 256 * HID) return;
    int layer = idx / (256 * HID);
    int rem = idx % (256 * HID);
    int row = rem / HID, col = rem % HID;
    const float* W = (row < 128) ? Wl : Wr;
    float v = W[(size_t)layer * HID * HID + (size_t)(row & 127) * HID + col];
    Wb[idx] = (short)f2bf(v);
}

// ---------------- register-tiled MFMA dual GEMM ----------------
template <int KPV>
__global__ __launch_bounds__(256) void k_gemm_rt(
    const short* __restrict__ A, const short* __restrict__ W,
    ushort* __restrict__ Yb, ushort* __restrict__ Rb, int M)
{
    constexpr int NK = KPV / 32;
    int wave = threadIdx.x >> 6;
    int lane = threadIdx.x & 63;
    int lr = lane & 15;
    int kg = lane >> 4;
    int m0 = blockIdx.x * 64;
    int wc = wave * 64;

    f32x4 acc[4][4];
#pragma unroll
    for (int i = 0; i < 4; i++)
#pragma unroll
        for (int j = 0; j < 4; j++) acc[i][j] = {0.f, 0.f, 0.f, 0.f};

    const short* abase = A + (size_t)(m0 + lr) * KPV + kg * 8;
    const short* wbase = W + (size_t)(wc + lr) * KPV + kg * 8;

#pragma unroll
    for (int ks = 0; ks < NK; ks++) {
        bf16x8 a[4], b[4];
#pragma unroll
        for (int rt = 0; rt < 4; rt++)
            a[rt] = *(const bf16x8*)(abase + (size_t)rt * 16 * KPV + ks * 32);
#pragma unroll
        for (int ntl = 0; ntl < 4; ntl++)
            b[ntl] = *(const bf16x8*)(wbase + (size_t)ntl * 16 * KPV + ks * 32);
#pragma unroll
        for (int rt = 0; rt < 4; rt++)
#pragma unroll
            for (int ntl = 0; ntl < 4; ntl++)
                acc[rt][ntl] = __builtin_amdgcn_mfma_f32_16x16x32_bf16(a[rt], b[ntl], acc[rt][ntl], 0, 0, 0);
    }

#pragma unroll
    for (int rt = 0; rt < 4; rt++) {
#pragma unroll
        for (int ntl = 0; ntl < 4; ntl++) {
            int c = wc + ntl * 16 + lr;
#pragma unroll
            for (int r = 0; r < 4; r++) {
                float v = acc[rt][ntl][r];
                float vp = __shfl_xor(v, 1);
                unsigned pk = (unsigned)f2bf(v) | ((unsigned)f2bf(vp) << 16);
                int node = m0 + rt * 16 + kg * 4 + r;
                if (!(lr & 1) && node < M) {
                    ushort* dstp = (c < HID) ? (Yb + (size_t)node * HID + c)
                                             : (Rb + (size_t)node * HID + (c - HID));
                    *(unsigned*)dstp = pk;
                }
            }
        }
    }
}

// ---------------- fused aggregate + bias + root + (LN) + ReLU (+ final proj) ----------------
// one wave per node; lane owns features 2*lane, 2*lane+1; 16-deep gather pipeline
__global__ __launch_bounds__(256) void k_aggregate(
    const ushort* __restrict__ Yb, const ushort* __restrict__ Rm,
    const ushort* __restrict__ Hres,
    const int* __restrict__ rowptr, const int* __restrict__ esrc,
    const float* __restrict__ bias, ushort* __restrict__ HbOut,
    const float* __restrict__ lW, const float* __restrict__ lb,
    float* __restrict__ out, int N, int mode)
{
    int lane = threadIdx.x & 63;
    int node = blockIdx.x * 4 + (threadIdx.x >> 6);
    if (node >= N) return;
    int beg = rowptr[node], end = rowptr[node + 1];
    const ushort* yb_lane = Yb + lane * 2;   // per-lane base; row offset = s*HID
    float s0 = 0.f, s1 = 0.f;
    for (int c0 = beg; c0 < end; c0 += 64) {
        int cnt = end - c0; if (cnt > 64) cnt = 64;
        int ids = (c0 + lane < end) ? esrc[c0 + lane] : 0;
        int t = 0;
        for (; t + 15 < cnt; t += 16) {   // 16 gathers in flight
            unsigned p[16];
#pragma unroll
            for (int u = 0; u < 16; u++) {
                int s = __shfl(ids, t + u);
                p[u] = *(const unsigned*)(yb_lane + (size_t)s * HID);
            }
#pragma unroll
            for (int u = 0; u < 16; u++) { s0 += bflo(p[u]); s1 += bfhi(p[u]); }
        }
        for (; t + 3 < cnt; t += 4) {
            unsigned p[4];
#pragma unroll
            for (int u = 0; u < 4; u++) {
                int s = __shfl(ids, t + u);
                p[u] = *(const unsigned*)(yb_lane + (size_t)s * HID);
            }
#pragma unroll
            for (int u = 0; u < 4; u++) { s0 += bflo(p[u]); s1 += bfhi(p[u]); }
        }
        for (; t < cnt; t++) {
            int s = __shfl(ids, t);
            unsigned pa = *(const unsigned*)(yb_lane + (size_t)s * HID);
            s0 += bflo(pa);
            s1 += bfhi(pa);
        }
    }
    float inv = 1.0f / fmaxf((float)(end - beg), 1.0f);
    size_t base = (size_t)node * HID;
    float2 b2 = *(const float2*)(bias + 2 * lane);
    unsigned r2 = *(const unsigned*)(Rm + base + 2 * lane);
    float v0 = s0 * inv + b2.x + bflo(r2);
    float v1 = s1 * inv + b2.y + bfhi(r2);
    float o0, o1;
    if (mode == 0) {
        o0 = fmaxf(v0, 0.f);
        o1 = fmaxf(v1, 0.f);
    } else {
        unsigned h2 = *(const unsigned*)(Hres + base + 2 * lane);
        float z0 = v0 + bflo(h2);
        float z1 = v1 + bfhi(h2);
        float sum = z0 + z1;
#pragma unroll
        for (int off = 32; off; off >>= 1) sum += __shfl_xor(sum, off);
        float mu = sum * (1.f / 128.f);
        float d0 = z0 - mu, d1 = z1 - mu;
        float vs = d0 * d0 + d1 * d1;
#pragma unroll
        for (int off = 32; off; off >>= 1) vs += __shfl_xor(vs, off);
        float rstd = rsqrtf(vs * (1.f / 128.f) + 1e-5f);
        o0 = fmaxf(d0 * rstd, 0.f);
        o1 = fmaxf(d1 * rstd, 0.f);
    }
    if (mode == 2) {
        float2 w0 = *(const float2*)(lW + 2 * lane);
        float2 w1 = *(const float2*)(lW + 128 + 2 * lane);
        float p0 = o0 * w0.x + o1 * w0.y;
        float p1 = o0 * w1.x + o1 * w1.y;
#pragma unroll
        for (int off = 32; off; off >>= 1) {
            p0 += __shfl_xor(p0, off);
            p1 += __shfl_xor(p1, off);
        }
        if (lane == 0) {
            out[(size_t)node * 2 + 0] = p0 + lb[0];
            out[(size_t)node * 2 + 1] = p1 + lb[1];
        }
    } else {
        unsigned pk = (unsigned)f2bf(o0) | ((unsigned)f2bf(o1) << 16);
        *(unsigned*)(HbOut + base + 2 * lane) = pk;
    }
}

extern "C" void kernel_launch(void* const* d_in, const int* in_sizes, int n_in,
                              void* d_out, int out_size, void* d_ws, size_t ws_size,
                              hipStream_t stream) {
    const int N = N_NODES, E = N_EDGES;
    const float* x   = (const float*)d_in[0];
    const int*   ei  = (const int*)d_in[1];
    const float* Wl0 = (const float*)d_in[2];
    const float* bl0 = (const float*)d_in[3];
    const float* Wr0 = (const float*)d_in[4];
    const float* Wl  = (const float*)d_in[5];
    const float* bl  = (const float*)d_in[6];
    const float* Wr  = (const float*)d_in[7];
    const float* lW  = (const float*)d_in[8];
    const float* lb  = (const float*)d_in[9];
    float* out = (float*)d_out;

    const int* src = ei;
    const int* dst = ei + E;

    const int PADR = 64;
    const int NP = ((N + 63) / 64) * 64;

    char* w = (char*)d_ws;
    ushort* Yb  = (ushort*)w; w += (size_t)(N + PADR) * HID * sizeof(ushort);
    ushort* Rb  = (ushort*)w; w += (size_t)(N + PADR) * HID * sizeof(ushort);
    ushort* Hb  = (ushort*)w; w += (size_t)(N + PADR) * HID * sizeof(ushort);
    ushort* xb  = (ushort*)w; w += (size_t)(N + PADR) * KP0 * sizeof(ushort);
    short*  Wb0 = (short*)w;  w += (size_t)256 * KP0 * sizeof(short);
    short*  Wb12= (short*)w;  w += (size_t)2 * 256 * HID * sizeof(short);
    int* counts = (int*)w;    w += (size_t)NBLK1 * NBKT * sizeof(int);
    int* offs   = (int*)w;    w += (size_t)NBLK1 * NBKT * sizeof(int);
    int* counts2= (int*)w;    w += (size_t)NBLK1 * NSB * sizeof(int);
    int* offs2  = (int*)w;    w += (size_t)NBLK1 * NSB * sizeof(int);
    int* bbase  = (int*)w;    w += (size_t)NBKT * sizeof(int);
    int* rowptr = (int*)w;    w += (size_t)(N + 1) * sizeof(int);
    int* ebuf   = (int*)w;    w += (size_t)E * sizeof(int);
    int* esrc   = (int*)w;    w += (size_t)E * sizeof(int);
    int2* ebuf2 = (int2*)w;   w += (size_t)E * sizeof(int2);

    const int nbGemm = (N + 63) / 64;
    const int nbNode = (N + 3) / 4;

    // src-bucket pre-sort, then stable dst counting sort -> CSR with src-bucket-ordered lists
    k_s1<<<NBLK1, 256, 0, stream>>>(src, counts2, E);
    k_s2<<<1, 64, 0, stream>>>(counts2, offs2);
    k_s3<<<NBLK1, 256, 0, stream>>>(src, dst, offs2, ebuf2, E);
    k_p1<<<NBLK1, 256, 0, stream>>>(ebuf2, counts, E);
    k_p2<<<1, 256, 0, stream>>>(counts, offs, bbase, rowptr, E);
    k_p3<<<NBLK1, 256, 0, stream>>>(ebuf2, offs, ebuf, E);
    k_p4<<<NBKT, 256, 0, stream>>>(ebuf, bbase, rowptr, esrc, E, N);

    // casts
    k_cast_x<<<(NP * (KP0 / 8) + 255) / 256, 256, 0, stream>>>(x, xb, NP);
    k_cast_w0<<<(256 * KP0 + 255) / 256, 256, 0, stream>>>(Wl0, Wr0, Wb0);
    k_cast_w12<<<(2 * 256 * HID + 255) / 256, 256, 0, stream>>>(Wl, Wr, Wb12);

    // layer 0
    k_gemm_rt<KP0><<<nbGemm, 256, 0, stream>>>((const short*)xb, Wb0, Yb, Rb, N);
    k_aggregate<<<nbNode, 256, 0, stream>>>(Yb, Rb, nullptr, rowptr, esrc, bl0, Hb,
                                            nullptr, nullptr, nullptr, N, 0);

    // layer 1
    k_gemm_rt<HID><<<nbGemm, 256, 0, stream>>>((const short*)Hb, Wb12, Yb, Rb, N);
    k_aggregate<<<nbNode, 256, 0, stream>>>(Yb, Rb, Hb, rowptr, esrc, bl, Hb,
                                            nullptr, nullptr, nullptr, N, 1);

    // layer 2 + fused final projection
    k_gemm_rt<HID><<<nbGemm, 256, 0, stream>>>((const short*)Hb, Wb12 + 256 * HID, Yb, Rb, N);
    k_aggregate<<<nbNode, 256, 0, stream>>>(Yb, Rb, Hb, rowptr, esrc, bl + HID, nullptr,
                                            lW, lb, out, N, 2);
}